// Round 4
// baseline (611.873 us; speedup 1.0000x reference)
//
#include <hip/hip_runtime.h>
#include <hip/hip_bf16.h>

#define LSPANS 4096
#define BB 32
#define HH 1024
#define DD 1024
#define VV 32000
#define K1 2048   // 2H
#define NT2 250   // V / 128

typedef unsigned short u16;
typedef __attribute__((ext_vector_type(8))) short bf16x8v;
typedef __attribute__((ext_vector_type(4))) float f32x4v;

__device__ __forceinline__ u16 f2bf(float x) {
  union { float f; unsigned u; } v; v.f = x;
  unsigned r = (v.u >> 16) & 1u;
  return (u16)((v.u + 0x7fffu + r) >> 16);
}

// ---------------- prep1: gather span endpoints + cvt W1 (fused) ----------
// blocks [0, LSPANS)            : gather two hidden rows -> bf16 A1[l, 2H]
// blocks [LSPANS, LSPANS+512)   : grid-stride f32->bf16 convert of W1
__global__ void prep1_kernel(const float* __restrict__ hidden,
                             const int* __restrict__ bid,
                             const int* __restrict__ sb,
                             const int* __restrict__ se,
                             u16* __restrict__ A1,
                             const float* __restrict__ W1,
                             u16* __restrict__ W1b) {
  const int blk = blockIdx.x;
  if (blk < LSPANS) {
    const int l = blk;
    const int t = threadIdx.x;  // 256 threads, 4 floats each per half
    const int b = bid[l];
    const float* p0 = hidden + ((size_t)sb[l] * BB + b) * HH;
    const float* p1 = hidden + ((size_t)se[l] * BB + b) * HH;
    u16* dst = A1 + (size_t)l * K1;
    float4 v0 = ((const float4*)p0)[t];
    float4 v1 = ((const float4*)p1)[t];
    ushort4 o0; o0.x = f2bf(v0.x); o0.y = f2bf(v0.y); o0.z = f2bf(v0.z); o0.w = f2bf(v0.w);
    ushort4 o1; o1.x = f2bf(v1.x); o1.y = f2bf(v1.y); o1.z = f2bf(v1.z); o1.w = f2bf(v1.w);
    ((ushort4*)dst)[t]          = o0;
    ((ushort4*)(dst + HH))[t]   = o1;
  } else {
    const int n4 = DD * K1 / 4;
    int i = (blk - LSPANS) * 256 + threadIdx.x;
    const int stride = 512 * 256;
    for (; i < n4; i += stride) {
      float4 v = ((const float4*)W1)[i];
      ushort4 o;
      o.x = f2bf(v.x); o.y = f2bf(v.y); o.z = f2bf(v.z); o.w = f2bf(v.w);
      ((ushort4*)W1b)[i] = o;
    }
  }
}

// ---------------- prep2: GEMM1 (128x64) + cvt Wout (fused, concurrent) ----
// blocks [0, 512)      : feat = tanh(A1 @ W1b^T + b1), proven round-3 body.
//                        Placed FIRST so all GEMM1 blocks are resident
//                        immediately; cvt blocks fill the remaining slots and
//                        stream HBM while GEMM1 waves occupy the MFMA pipe.
// blocks [512, 2560)   : grid-stride f32->bf16 convert of Wout (196 MB).
__launch_bounds__(256, 2)
__global__ void prep2_kernel(const u16* __restrict__ A, const u16* __restrict__ B,
                             const float* __restrict__ bias,
                             u16* __restrict__ feat_out,
                             const float* __restrict__ Wout,
                             u16* __restrict__ Woutb) {
  __shared__ __align__(16) u16 As[128 * 64];
  __shared__ __align__(16) u16 Bs[64 * 64];

  if (blockIdx.x < 512) {
    const int tid  = threadIdx.x;
    const int lane = tid & 63;
    const int w    = tid >> 6;
    const int wm   = w & 1;
    const int wn   = w >> 1;
    const int q    = lane >> 4;
    const int lm   = lane & 15;
    const int mBase = (blockIdx.x & 31) * 128;   // 32 M-tiles
    const int nBase = (blockIdx.x >> 5) * 64;    // 16 N-tiles

    f32x4v acc[4][2];
#pragma unroll
    for (int i = 0; i < 4; ++i)
#pragma unroll
      for (int j = 0; j < 2; ++j) acc[i][j] = (f32x4v){0.f, 0.f, 0.f, 0.f};

    const int srowA = w * 32 + (lane >> 3);
    const int srowB = w * 16 + (lane >> 3);
    const int scol  = ((lane & 7) ^ (lane >> 3)) * 8;   // swizzled source column
    const u16* Ag = A + (size_t)(mBase + srowA) * K1 + scol;
    const u16* Bg = B + (size_t)(nBase + srowB) * K1 + scol;

    for (int k0 = 0; k0 < K1; k0 += 64) {
#pragma unroll
      for (int c = 0; c < 4; ++c) {
        __builtin_amdgcn_global_load_lds(
            (const __attribute__((address_space(1))) void*)(Ag + k0 + (size_t)c * 8 * K1),
            (__attribute__((address_space(3))) void*)(As + (w * 32 + c * 8) * 64), 16, 0, 0);
      }
#pragma unroll
      for (int c = 0; c < 2; ++c) {
        __builtin_amdgcn_global_load_lds(
            (const __attribute__((address_space(1))) void*)(Bg + k0 + (size_t)c * 8 * K1),
            (__attribute__((address_space(3))) void*)(Bs + (w * 16 + c * 8) * 64), 16, 0, 0);
      }
      __syncthreads();
#pragma unroll
      for (int kk = 0; kk < 64; kk += 32) {
        bf16x8v af[4], bfr[2];
        const int sw = lm & 7;
#pragma unroll
        for (int i = 0; i < 4; ++i) {
          int row = wm * 64 + i * 16 + lm;
          int kch = (kk >> 3) + q;
          af[i] = *(const bf16x8v*)(As + row * 64 + ((kch ^ sw) << 3));
        }
#pragma unroll
        for (int j = 0; j < 2; ++j) {
          int row = wn * 32 + j * 16 + lm;
          int kch = (kk >> 3) + q;
          bfr[j] = *(const bf16x8v*)(Bs + row * 64 + ((kch ^ sw) << 3));
        }
#pragma unroll
        for (int i = 0; i < 4; ++i)
#pragma unroll
          for (int j = 0; j < 2; ++j)
            acc[i][j] = __builtin_amdgcn_mfma_f32_16x16x32_bf16(af[i], bfr[j], acc[i][j], 0, 0, 0);
      }
      __syncthreads();
    }

    float bj[2];
#pragma unroll
    for (int j = 0; j < 2; ++j) bj[j] = bias[nBase + wn * 32 + j * 16 + lm];
#pragma unroll
    for (int i = 0; i < 4; ++i)
#pragma unroll
      for (int j = 0; j < 2; ++j)
#pragma unroll
        for (int r = 0; r < 4; ++r) {
          int tr = wm * 64 + i * 16 + q * 4 + r;
          int tc = wn * 32 + j * 16 + lm;
          float v = tanhf(acc[i][j][r] + bj[j]);
          feat_out[(size_t)(mBase + tr) * DD + nBase + tc] = f2bf(v);
        }
  } else {
    const int n4 = VV * DD / 4;
    int i = (blockIdx.x - 512) * 256 + threadIdx.x;
    const int stride = 2048 * 256;
    for (; i < n4; i += stride) {
      float4 v = ((const float4*)Wout)[i];
      ushort4 o;
      o.x = f2bf(v.x); o.y = f2bf(v.y); o.z = f2bf(v.z); o.w = f2bf(v.w);
      ((ushort4*)Woutb)[i] = o;
    }
  }
}

// ---------------- 128x128 MFMA GEMM2 (round-0 proven K-loop) --------------
// LDS layout is XOR-swizzled: LDS[r][chunk c] holds global chunk (c ^ (r&7)),
// chunks are 8 u16 = 16 B; swizzle applied on the global SOURCE address.
// Fragment reads use chunk = kch ^ (row&7).
// Added this round: T1 bijective XCD swizzle on the block mapping only
// (8000 blocks, 8000 % 8 == 0 -> (lin&7)*1000 + lin>>3). Each XCD gets a
// contiguous run of 1000 tiles = ~31 full B-panels reused within its own L2.
__launch_bounds__(256, 2)
__global__ void gemm2_kernel(const u16* __restrict__ A, const u16* __restrict__ B,
                             const int* __restrict__ tags,
                             float* __restrict__ pmax, float* __restrict__ psum,
                             float* __restrict__ ltag) {
  __shared__ __align__(16) u16 As[128 * 64];
  __shared__ __align__(16) u16 Bs[128 * 64];
  __shared__ float rmax[2][128];
  __shared__ float rsum[2][128];
  __shared__ int   stags[128];

  const int tid  = threadIdx.x;
  const int lane = tid & 63;
  const int w    = tid >> 6;       // wave 0..3
  const int wm   = w & 1;          // wave row (M)
  const int wn   = w >> 1;         // wave col (N)
  const int q    = lane >> 4;      // quad 0..3
  const int lm   = lane & 15;
  // XCD swizzle: grid (32, 250), linear id x-fastest; 8000/8 = 1000 per XCD
  const int lin = blockIdx.y * 32 + blockIdx.x;
  const int nl  = (lin & 7) * 1000 + (lin >> 3);
  const int bx  = nl & 31;
  const int by  = nl >> 5;
  const int mBase = bx * 128;
  const int nBase = by * 128;

  if (tid < 128) stags[tid] = tags[mBase + tid];

  f32x4v acc[4][4];
#pragma unroll
  for (int i = 0; i < 4; ++i)
#pragma unroll
    for (int j = 0; j < 4; ++j) acc[i][j] = (f32x4v){0.f, 0.f, 0.f, 0.f};

  const int srow = w * 32 + (lane >> 3);
  const int scol = ((lane & 7) ^ (lane >> 3)) * 8;   // swizzled source column
  const u16* Ag = A + (size_t)(mBase + srow) * DD + scol;
  const u16* Bg = B + (size_t)(nBase + srow) * DD + scol;

  for (int k0 = 0; k0 < DD; k0 += 64) {
#pragma unroll
    for (int c = 0; c < 4; ++c) {
      __builtin_amdgcn_global_load_lds(
          (const __attribute__((address_space(1))) void*)(Ag + k0 + (size_t)c * 8 * DD),
          (__attribute__((address_space(3))) void*)(As + (w * 32 + c * 8) * 64), 16, 0, 0);
    }
#pragma unroll
    for (int c = 0; c < 4; ++c) {
      __builtin_amdgcn_global_load_lds(
          (const __attribute__((address_space(1))) void*)(Bg + k0 + (size_t)c * 8 * DD),
          (__attribute__((address_space(3))) void*)(Bs + (w * 32 + c * 8) * 64), 16, 0, 0);
    }
    __syncthreads();
#pragma unroll
    for (int kk = 0; kk < 64; kk += 32) {
      bf16x8v af[4], bfr[4];
      const int sw = lm & 7;
#pragma unroll
      for (int i = 0; i < 4; ++i) {
        int row = wm * 64 + i * 16 + lm;
        int kch = (kk >> 3) + q;
        af[i] = *(const bf16x8v*)(As + row * 64 + ((kch ^ sw) << 3));
      }
#pragma unroll
      for (int j = 0; j < 4; ++j) {
        int row = wn * 64 + j * 16 + lm;
        int kch = (kk >> 3) + q;
        bfr[j] = *(const bf16x8v*)(Bs + row * 64 + ((kch ^ sw) << 3));
      }
#pragma unroll
      for (int i = 0; i < 4; ++i)
#pragma unroll
        for (int j = 0; j < 4; ++j)
          acc[i][j] = __builtin_amdgcn_mfma_f32_16x16x32_bf16(af[i], bfr[j], acc[i][j], 0, 0, 0);
    }
    __syncthreads();
  }

  // C/D layout: col = lane&15, row = quad*4 + reg
  // phase 1: per-row max over this wave's 64 cols -> LDS
#pragma unroll
  for (int i = 0; i < 4; ++i)
#pragma unroll
    for (int r = 0; r < 4; ++r) {
      float m = fmaxf(fmaxf(acc[i][0][r], acc[i][1][r]),
                      fmaxf(acc[i][2][r], acc[i][3][r]));
#pragma unroll
      for (int off = 1; off < 16; off <<= 1) m = fmaxf(m, __shfl_xor(m, off, 64));
      if (lm == 0) rmax[wn][wm * 64 + i * 16 + q * 4 + r] = m;
    }
  __syncthreads();
  // phase 2: sumexp against the full 128-col row max
#pragma unroll
  for (int i = 0; i < 4; ++i)
#pragma unroll
    for (int r = 0; r < 4; ++r) {
      int tr = wm * 64 + i * 16 + q * 4 + r;
      float M = fmaxf(rmax[0][tr], rmax[1][tr]);
      float s = __expf(acc[i][0][r] - M) + __expf(acc[i][1][r] - M) +
                __expf(acc[i][2][r] - M) + __expf(acc[i][3][r] - M);
#pragma unroll
      for (int off = 1; off < 16; off <<= 1) s += __shfl_xor(s, off, 64);
      if (lm == 0) rsum[wn][tr] = s;
    }
  __syncthreads();
  if (tid < 128) {
    float M = fmaxf(rmax[0][tid], rmax[1][tid]);
    float S = rsum[0][tid] + rsum[1][tid];
    pmax[(size_t)by * LSPANS + mBase + tid] = M;
    psum[(size_t)by * LSPANS + mBase + tid] = S;
  }
  // tag logit capture (exactly one matching column per row globally)
#pragma unroll
  for (int i = 0; i < 4; ++i)
#pragma unroll
    for (int r = 0; r < 4; ++r) {
      int tr = wm * 64 + i * 16 + q * 4 + r;
      int tg = stags[tr];
#pragma unroll
      for (int j = 0; j < 4; ++j) {
        int gc = nBase + wn * 64 + j * 16 + lm;
        if (tg == gc) ltag[mBase + tr] = acc[i][j][r];
      }
    }
}

// ---------------- merge partials, weighted-mean NLL (wave-per-row) ----------
// pmax/psum layout: [tile t][row l] (t < NT2=250, stride LSPANS).
// One wave per row: lane L caches tiles t = L, L+64, L+128, L+192 in regs,
// butterfly max, then butterfly sum of psum*exp(pmax-M).
__global__ void finalize_kernel(const float* __restrict__ pmax, const float* __restrict__ psum,
                                const float* __restrict__ ltag, const int* __restrict__ tags,
                                const float* __restrict__ dprob, float* __restrict__ out) {
  const int lane = threadIdx.x & 63;
  const int wv   = threadIdx.x >> 6;
  const int row  = blockIdx.x * 4 + wv;

  float pmv[4], psv[4];
#pragma unroll
  for (int it = 0; it < 4; ++it) {
    int t = lane + it * 64;
    bool ok = t < NT2;
    pmv[it] = ok ? pmax[(size_t)t * LSPANS + row] : -1e30f;
    psv[it] = ok ? psum[(size_t)t * LSPANS + row] : 0.f;
  }
  float M = fmaxf(fmaxf(pmv[0], pmv[1]), fmaxf(pmv[2], pmv[3]));
#pragma unroll
  for (int off = 1; off < 64; off <<= 1) M = fmaxf(M, __shfl_xor(M, off, 64));
  float s = 0.f;
#pragma unroll
  for (int it = 0; it < 4; ++it) s += psv[it] * __expf(pmv[it] - M);
#pragma unroll
  for (int off = 1; off < 64; off <<= 1) s += __shfl_xor(s, off, 64);

  __shared__ float red[4];
  if (lane == 0) {
    float nll = M + logf(s) - ltag[row];
    float wgt = 1.0f - dprob[tags[row]];
    red[wv] = nll * wgt * (1.0f / (4096.0f + 1e-5f));
  }
  __syncthreads();
  if (threadIdx.x == 0) atomicAdd(out, red[0] + red[1] + red[2] + red[3]);
}

extern "C" void kernel_launch(void* const* d_in, const int* in_sizes, int n_in,
                              void* d_out, int out_size, void* d_ws, size_t ws_size,
                              hipStream_t stream) {
  const float* hidden = (const float*)d_in[0];
  const float* W1     = (const float*)d_in[1];
  const float* b1     = (const float*)d_in[2];
  const float* Wout   = (const float*)d_in[3];
  const float* dprob  = (const float*)d_in[4];
  const int*   bid    = (const int*)d_in[5];
  const int*   sb     = (const int*)d_in[6];
  const int*   se     = (const int*)d_in[7];
  const int*   tags   = (const int*)d_in[8];
  float* out = (float*)d_out;

  char* ws = (char*)d_ws;
  u16* A1    = (u16*)ws;                 ws += (size_t)LSPANS * K1 * 2;      // 16.78 MB
  u16* W1b   = (u16*)ws;                 ws += (size_t)DD * K1 * 2;          //  4.19 MB
  u16* Woutb = (u16*)ws;                 ws += (size_t)VV * DD * 2;          // 65.54 MB
  u16* feat  = (u16*)ws;                 ws += (size_t)LSPANS * DD * 2;      //  8.39 MB
  float* pmax = (float*)ws;              ws += (size_t)NT2 * LSPANS * 4;     //  4.10 MB
  float* psum = (float*)ws;              ws += (size_t)NT2 * LSPANS * 4;     //  4.10 MB
  float* ltag = (float*)ws;              ws += (size_t)LSPANS * 4;

  hipMemsetAsync(d_out, 0, sizeof(float), stream);

  // prep1: gather span endpoints + cvt W1 (fused)
  prep1_kernel<<<LSPANS + 512, 256, 0, stream>>>(hidden, bid, sb, se, A1, W1, W1b);

  // prep2: GEMM1 (512 blocks, resident first) + cvt Wout (2048 grid-stride)
  prep2_kernel<<<512 + 2048, 256, 0, stream>>>(A1, W1b, b1, feat, Wout, Woutb);

  // GEMM2: logits tiles + fused softmax partials   [4096 x 32000]
  gemm2_kernel<<<dim3(32, NT2), 256, 0, stream>>>(
      feat, Woutb, tags, pmax, psum, ltag);

  // merge + weighted mean
  finalize_kernel<<<LSPANS / 4, 256, 0, stream>>>(pmax, psum, ltag, tags, dprob, out);
}

// Round 5
// 605.444 us; speedup vs baseline: 1.0106x; 1.0106x over previous
//
#include <hip/hip_runtime.h>
#include <hip/hip_bf16.h>

#define LSPANS 4096
#define BB 32
#define HH 1024
#define DD 1024
#define VV 32000
#define K1 2048   // 2H
#define NT2 250   // V / 128

typedef unsigned short u16;
typedef __attribute__((ext_vector_type(8))) short bf16x8v;
typedef __attribute__((ext_vector_type(4))) float f32x4v;

__device__ __forceinline__ u16 f2bf(float x) {
  union { float f; unsigned u; } v; v.f = x;
  unsigned r = (v.u >> 16) & 1u;
  return (u16)((v.u + 0x7fffu + r) >> 16);
}

// ---------------- prep1: gather span endpoints + cvt W1 (fused) ----------
// blocks [0, LSPANS)            : gather two hidden rows -> bf16 A1[l, 2H]
// blocks [LSPANS, LSPANS+512)   : grid-stride f32->bf16 convert of W1
__global__ void prep1_kernel(const float* __restrict__ hidden,
                             const int* __restrict__ bid,
                             const int* __restrict__ sb,
                             const int* __restrict__ se,
                             u16* __restrict__ A1,
                             const float* __restrict__ W1,
                             u16* __restrict__ W1b) {
  const int blk = blockIdx.x;
  if (blk < LSPANS) {
    const int l = blk;
    const int t = threadIdx.x;  // 256 threads, 4 floats each per half
    const int b = bid[l];
    const float* p0 = hidden + ((size_t)sb[l] * BB + b) * HH;
    const float* p1 = hidden + ((size_t)se[l] * BB + b) * HH;
    u16* dst = A1 + (size_t)l * K1;
    float4 v0 = ((const float4*)p0)[t];
    float4 v1 = ((const float4*)p1)[t];
    ushort4 o0; o0.x = f2bf(v0.x); o0.y = f2bf(v0.y); o0.z = f2bf(v0.z); o0.w = f2bf(v0.w);
    ushort4 o1; o1.x = f2bf(v1.x); o1.y = f2bf(v1.y); o1.z = f2bf(v1.z); o1.w = f2bf(v1.w);
    ((ushort4*)dst)[t]          = o0;
    ((ushort4*)(dst + HH))[t]   = o1;
  } else {
    const int n4 = DD * K1 / 4;
    int i = (blk - LSPANS) * 256 + threadIdx.x;
    const int stride = 512 * 256;
    for (; i < n4; i += stride) {
      float4 v = ((const float4*)W1)[i];
      ushort4 o;
      o.x = f2bf(v.x); o.y = f2bf(v.y); o.z = f2bf(v.z); o.w = f2bf(v.w);
      ((ushort4*)W1b)[i] = o;
    }
  }
}

// ---------------- prep2: GEMM1 (128x64) + cvt Wout (fused, concurrent) ----
// blocks [0, 512)      : feat = tanh(A1 @ W1b^T + b1), proven round-3 body.
//                        GEMM1 blocks dispatch first (resident immediately);
//                        cvt blocks fill remaining CU slots and stream HBM
//                        while GEMM1 waves occupy the MFMA pipe (m114 overlap).
// blocks [512, 2560)   : grid-stride f32->bf16 convert of Wout (196 MB).
__launch_bounds__(256, 2)
__global__ void prep2_kernel(const u16* __restrict__ A, const u16* __restrict__ B,
                             const float* __restrict__ bias,
                             u16* __restrict__ feat_out,
                             const float* __restrict__ Wout,
                             u16* __restrict__ Woutb) {
  __shared__ __align__(16) u16 As[128 * 64];
  __shared__ __align__(16) u16 Bs[64 * 64];

  if (blockIdx.x < 512) {
    const int tid  = threadIdx.x;
    const int lane = tid & 63;
    const int w    = tid >> 6;
    const int wm   = w & 1;
    const int wn   = w >> 1;
    const int q    = lane >> 4;
    const int lm   = lane & 15;
    const int mBase = (blockIdx.x & 31) * 128;   // 32 M-tiles
    const int nBase = (blockIdx.x >> 5) * 64;    // 16 N-tiles

    f32x4v acc[4][2];
#pragma unroll
    for (int i = 0; i < 4; ++i)
#pragma unroll
      for (int j = 0; j < 2; ++j) acc[i][j] = (f32x4v){0.f, 0.f, 0.f, 0.f};

    const int srowA = w * 32 + (lane >> 3);
    const int srowB = w * 16 + (lane >> 3);
    const int scol  = ((lane & 7) ^ (lane >> 3)) * 8;   // swizzled source column
    const u16* Ag = A + (size_t)(mBase + srowA) * K1 + scol;
    const u16* Bg = B + (size_t)(nBase + srowB) * K1 + scol;

    for (int k0 = 0; k0 < K1; k0 += 64) {
#pragma unroll
      for (int c = 0; c < 4; ++c) {
        __builtin_amdgcn_global_load_lds(
            (const __attribute__((address_space(1))) void*)(Ag + k0 + (size_t)c * 8 * K1),
            (__attribute__((address_space(3))) void*)(As + (w * 32 + c * 8) * 64), 16, 0, 0);
      }
#pragma unroll
      for (int c = 0; c < 2; ++c) {
        __builtin_amdgcn_global_load_lds(
            (const __attribute__((address_space(1))) void*)(Bg + k0 + (size_t)c * 8 * K1),
            (__attribute__((address_space(3))) void*)(Bs + (w * 16 + c * 8) * 64), 16, 0, 0);
      }
      __syncthreads();
#pragma unroll
      for (int kk = 0; kk < 64; kk += 32) {
        bf16x8v af[4], bfr[2];
        const int sw = lm & 7;
#pragma unroll
        for (int i = 0; i < 4; ++i) {
          int row = wm * 64 + i * 16 + lm;
          int kch = (kk >> 3) + q;
          af[i] = *(const bf16x8v*)(As + row * 64 + ((kch ^ sw) << 3));
        }
#pragma unroll
        for (int j = 0; j < 2; ++j) {
          int row = wn * 32 + j * 16 + lm;
          int kch = (kk >> 3) + q;
          bfr[j] = *(const bf16x8v*)(Bs + row * 64 + ((kch ^ sw) << 3));
        }
#pragma unroll
        for (int i = 0; i < 4; ++i)
#pragma unroll
          for (int j = 0; j < 2; ++j)
            acc[i][j] = __builtin_amdgcn_mfma_f32_16x16x32_bf16(af[i], bfr[j], acc[i][j], 0, 0, 0);
      }
      __syncthreads();
    }

    float bj[2];
#pragma unroll
    for (int j = 0; j < 2; ++j) bj[j] = bias[nBase + wn * 32 + j * 16 + lm];
#pragma unroll
    for (int i = 0; i < 4; ++i)
#pragma unroll
      for (int j = 0; j < 2; ++j)
#pragma unroll
        for (int r = 0; r < 4; ++r) {
          int tr = wm * 64 + i * 16 + q * 4 + r;
          int tc = wn * 32 + j * 16 + lm;
          float v = tanhf(acc[i][j][r] + bj[j]);
          feat_out[(size_t)(mBase + tr) * DD + nBase + tc] = f2bf(v);
        }
  } else {
    const int n4 = VV * DD / 4;
    int i = (blockIdx.x - 512) * 256 + threadIdx.x;
    const int stride = 2048 * 256;
    for (; i < n4; i += stride) {
      float4 v = ((const float4*)Wout)[i];
      ushort4 o;
      o.x = f2bf(v.x); o.y = f2bf(v.y); o.z = f2bf(v.z); o.w = f2bf(v.w);
      ((ushort4*)Woutb)[i] = o;
    }
  }
}

// ---------------- 128x128 MFMA GEMM2 (round-0 proven; NATURAL block map) ----
// LDS layout is XOR-swizzled: LDS[r][chunk c] holds global chunk (c ^ (r&7)),
// chunks are 8 u16 = 16 B; swizzle applied on the global SOURCE address.
// Fragment reads use chunk = kch ^ (row&7).
// NOTE: no XCD swizzle — round-4 measured FETCH 274->824 MB with the
// contiguous-per-XCD remap (natural x-fastest order keeps all XCDs in the
// same B-panel window; Wout streams through shared L3 once).
__launch_bounds__(256, 2)
__global__ void gemm2_kernel(const u16* __restrict__ A, const u16* __restrict__ B,
                             const int* __restrict__ tags,
                             float* __restrict__ pmax, float* __restrict__ psum,
                             float* __restrict__ ltag) {
  __shared__ __align__(16) u16 As[128 * 64];
  __shared__ __align__(16) u16 Bs[128 * 64];
  __shared__ float rmax[2][128];
  __shared__ float rsum[2][128];
  __shared__ int   stags[128];

  const int tid  = threadIdx.x;
  const int lane = tid & 63;
  const int w    = tid >> 6;       // wave 0..3
  const int wm   = w & 1;          // wave row (M)
  const int wn   = w >> 1;         // wave col (N)
  const int q    = lane >> 4;      // quad 0..3
  const int lm   = lane & 15;
  const int mBase = blockIdx.x * 128;
  const int nBase = blockIdx.y * 128;

  if (tid < 128) stags[tid] = tags[mBase + tid];

  f32x4v acc[4][4];
#pragma unroll
  for (int i = 0; i < 4; ++i)
#pragma unroll
    for (int j = 0; j < 4; ++j) acc[i][j] = (f32x4v){0.f, 0.f, 0.f, 0.f};

  const int srow = w * 32 + (lane >> 3);
  const int scol = ((lane & 7) ^ (lane >> 3)) * 8;   // swizzled source column
  const u16* Ag = A + (size_t)(mBase + srow) * DD + scol;
  const u16* Bg = B + (size_t)(nBase + srow) * DD + scol;

  for (int k0 = 0; k0 < DD; k0 += 64) {
#pragma unroll
    for (int c = 0; c < 4; ++c) {
      __builtin_amdgcn_global_load_lds(
          (const __attribute__((address_space(1))) void*)(Ag + k0 + (size_t)c * 8 * DD),
          (__attribute__((address_space(3))) void*)(As + (w * 32 + c * 8) * 64), 16, 0, 0);
    }
#pragma unroll
    for (int c = 0; c < 4; ++c) {
      __builtin_amdgcn_global_load_lds(
          (const __attribute__((address_space(1))) void*)(Bg + k0 + (size_t)c * 8 * DD),
          (__attribute__((address_space(3))) void*)(Bs + (w * 32 + c * 8) * 64), 16, 0, 0);
    }
    __syncthreads();
#pragma unroll
    for (int kk = 0; kk < 64; kk += 32) {
      bf16x8v af[4], bfr[4];
      const int sw = lm & 7;
#pragma unroll
      for (int i = 0; i < 4; ++i) {
        int row = wm * 64 + i * 16 + lm;
        int kch = (kk >> 3) + q;
        af[i] = *(const bf16x8v*)(As + row * 64 + ((kch ^ sw) << 3));
      }
#pragma unroll
      for (int j = 0; j < 4; ++j) {
        int row = wn * 64 + j * 16 + lm;
        int kch = (kk >> 3) + q;
        bfr[j] = *(const bf16x8v*)(Bs + row * 64 + ((kch ^ sw) << 3));
      }
#pragma unroll
      for (int i = 0; i < 4; ++i)
#pragma unroll
        for (int j = 0; j < 4; ++j)
          acc[i][j] = __builtin_amdgcn_mfma_f32_16x16x32_bf16(af[i], bfr[j], acc[i][j], 0, 0, 0);
    }
    __syncthreads();
  }

  // C/D layout: col = lane&15, row = quad*4 + reg
  // phase 1: per-row max over this wave's 64 cols -> LDS
#pragma unroll
  for (int i = 0; i < 4; ++i)
#pragma unroll
    for (int r = 0; r < 4; ++r) {
      float m = fmaxf(fmaxf(acc[i][0][r], acc[i][1][r]),
                      fmaxf(acc[i][2][r], acc[i][3][r]));
#pragma unroll
      for (int off = 1; off < 16; off <<= 1) m = fmaxf(m, __shfl_xor(m, off, 64));
      if (lm == 0) rmax[wn][wm * 64 + i * 16 + q * 4 + r] = m;
    }
  __syncthreads();
  // phase 2: sumexp against the full 128-col row max
#pragma unroll
  for (int i = 0; i < 4; ++i)
#pragma unroll
    for (int r = 0; r < 4; ++r) {
      int tr = wm * 64 + i * 16 + q * 4 + r;
      float M = fmaxf(rmax[0][tr], rmax[1][tr]);
      float s = __expf(acc[i][0][r] - M) + __expf(acc[i][1][r] - M) +
                __expf(acc[i][2][r] - M) + __expf(acc[i][3][r] - M);
#pragma unroll
      for (int off = 1; off < 16; off <<= 1) s += __shfl_xor(s, off, 64);
      if (lm == 0) rsum[wn][tr] = s;
    }
  __syncthreads();
  if (tid < 128) {
    float M = fmaxf(rmax[0][tid], rmax[1][tid]);
    float S = rsum[0][tid] + rsum[1][tid];
    pmax[(size_t)blockIdx.y * LSPANS + mBase + tid] = M;
    psum[(size_t)blockIdx.y * LSPANS + mBase + tid] = S;
  }
  // tag logit capture (exactly one matching column per row globally)
#pragma unroll
  for (int i = 0; i < 4; ++i)
#pragma unroll
    for (int r = 0; r < 4; ++r) {
      int tr = wm * 64 + i * 16 + q * 4 + r;
      int tg = stags[tr];
#pragma unroll
      for (int j = 0; j < 4; ++j) {
        int gc = nBase + wn * 64 + j * 16 + lm;
        if (tg == gc) ltag[mBase + tr] = acc[i][j][r];
      }
    }
}

// ---------------- merge partials, weighted-mean NLL (coalesced online) ------
// pmax/psum layout: [tile t][row l] (t < NT2=250, stride LSPANS).
// 64 blocks x 256 threads; lane = row offset (coalesced 256 B/instruction:
// 64 consecutive rows per load). Wave w owns tiles t = w, w+4, ... and merges
// them with an online max/sum (one pass, no re-read). 4-way combine via LDS.
__global__ void finalize_kernel(const float* __restrict__ pmax, const float* __restrict__ psum,
                                const float* __restrict__ ltag, const int* __restrict__ tags,
                                const float* __restrict__ dprob, float* __restrict__ out) {
  const int lane = threadIdx.x & 63;
  const int wv   = threadIdx.x >> 6;      // 0..3
  const int row  = blockIdx.x * 64 + lane;

  float M = -1e30f, S = 0.f;
  for (int t = wv; t < NT2; t += 4) {
    float pm = pmax[(size_t)t * LSPANS + row];
    float ps = psum[(size_t)t * LSPANS + row];
    float Mn = fmaxf(M, pm);
    S = S * __expf(M - Mn) + ps * __expf(pm - Mn);
    M = Mn;
  }

  __shared__ float lmax[4][64];
  __shared__ float lsum[4][64];
  lmax[wv][lane] = M;
  lsum[wv][lane] = S;
  __syncthreads();

  if (wv == 0) {
    float M0 = fmaxf(fmaxf(lmax[0][lane], lmax[1][lane]),
                     fmaxf(lmax[2][lane], lmax[3][lane]));
    float S0 = lsum[0][lane] * __expf(lmax[0][lane] - M0)
             + lsum[1][lane] * __expf(lmax[1][lane] - M0)
             + lsum[2][lane] * __expf(lmax[2][lane] - M0)
             + lsum[3][lane] * __expf(lmax[3][lane] - M0);
    float nll = M0 + logf(S0) - ltag[row];
    float wgt = 1.0f - dprob[tags[row]];
    float val = nll * wgt * (1.0f / (4096.0f + 1e-5f));
#pragma unroll
    for (int off = 1; off < 64; off <<= 1) val += __shfl_xor(val, off, 64);
    if (lane == 0) atomicAdd(out, val);
  }
}

extern "C" void kernel_launch(void* const* d_in, const int* in_sizes, int n_in,
                              void* d_out, int out_size, void* d_ws, size_t ws_size,
                              hipStream_t stream) {
  const float* hidden = (const float*)d_in[0];
  const float* W1     = (const float*)d_in[1];
  const float* b1     = (const float*)d_in[2];
  const float* Wout   = (const float*)d_in[3];
  const float* dprob  = (const float*)d_in[4];
  const int*   bid    = (const int*)d_in[5];
  const int*   sb     = (const int*)d_in[6];
  const int*   se     = (const int*)d_in[7];
  const int*   tags   = (const int*)d_in[8];
  float* out = (float*)d_out;

  char* ws = (char*)d_ws;
  u16* A1    = (u16*)ws;                 ws += (size_t)LSPANS * K1 * 2;      // 16.78 MB
  u16* W1b   = (u16*)ws;                 ws += (size_t)DD * K1 * 2;          //  4.19 MB
  u16* Woutb = (u16*)ws;                 ws += (size_t)VV * DD * 2;          // 65.54 MB
  u16* feat  = (u16*)ws;                 ws += (size_t)LSPANS * DD * 2;      //  8.39 MB
  float* pmax = (float*)ws;              ws += (size_t)NT2 * LSPANS * 4;     //  4.10 MB
  float* psum = (float*)ws;              ws += (size_t)NT2 * LSPANS * 4;     //  4.10 MB
  float* ltag = (float*)ws;              ws += (size_t)LSPANS * 4;

  hipMemsetAsync(d_out, 0, sizeof(float), stream);

  // prep1: gather span endpoints + cvt W1 (fused)
  prep1_kernel<<<LSPANS + 512, 256, 0, stream>>>(hidden, bid, sb, se, A1, W1, W1b);

  // prep2: GEMM1 (512 blocks, resident first) + cvt Wout (2048 grid-stride)
  prep2_kernel<<<512 + 2048, 256, 0, stream>>>(A1, W1b, b1, feat, Wout, Woutb);

  // GEMM2: logits tiles + fused softmax partials   [4096 x 32000]
  gemm2_kernel<<<dim3(LSPANS / 128, NT2), 256, 0, stream>>>(
      feat, Woutb, tags, pmax, psum, ltag);

  // merge + weighted mean
  finalize_kernel<<<LSPANS / 64, 256, 0, stream>>>(pmax, psum, ltag, tags, dprob, out);
}